// Round 13
// baseline (318.365 us; speedup 1.0000x reference)
//
#include <hip/hip_runtime.h>
#include <cstddef>
#include <cstdint>

#define Tn 52
#define Fn 64
#define Hn 32
#define Bn 8192
#define XHAT_ELEMS (Bn * Tn * Fn)   // fp32 elems of x_hat; xs1 bf16 plane fits in half
#define L2E 1.44269504088896340736f

typedef __attribute__((ext_vector_type(8))) short bf8v;   // 8 bf16 (4 VGPRs)
typedef __attribute__((ext_vector_type(4))) float f4v;    // 4 fp32 accum
typedef __attribute__((ext_vector_type(2))) float f2v;    // packed-f32 pair

__device__ __forceinline__ f4v mfma_bf16(bf8v a, bf8v b, f4v c) {
    return __builtin_amdgcn_mfma_f32_16x16x32_bf16(a, b, c, 0, 0, 0);
}

// RNE round to bf16
__device__ __forceinline__ unsigned short rne_bf16(float v) {
    unsigned b = __float_as_uint(v);
    unsigned r = ((b >> 16) & 1u) + 0x7FFFu;
    return (unsigned short)((b + r) >> 16);
}

__device__ __forceinline__ bf8v rne8(float4 a, float4 b) {
    float v[8] = {a.x, a.y, a.z, a.w, b.x, b.y, b.z, b.w};
    bf8v r;
#pragma unroll
    for (int j = 0; j < 8; ++j) r[j] = (short)rne_bf16(v[j]);
    return r;
}

// encoder barrier (best-measured R7 flavor): sched pins
__device__ __forceinline__ void lds_barrier_pinned() {
    __builtin_amdgcn_sched_barrier(0);
    asm volatile("s_waitcnt lgkmcnt(0)" ::: "memory");
    __builtin_amdgcn_s_barrier();
    __builtin_amdgcn_sched_barrier(0);
}

// decoder barrier (best-measured R8 flavor): relaxed
__device__ __forceinline__ void lds_barrier_relaxed() {
    asm volatile("s_waitcnt lgkmcnt(0)" ::: "memory");
    __builtin_amdgcn_s_barrier();
}

// exp2(min(40, -a)) elementwise on a pair (trans ops are scalar)
__device__ __forceinline__ f2v nexp2c(f2v a) {
    f2v r;
    r.x = exp2f(fminf(40.f, -a.x));
    r.y = exp2f(fminf(40.f, -a.y));
    return r;
}
__device__ __forceinline__ f2v rcp2(f2v a) {
    f2v r;
    r.x = __builtin_amdgcn_rcpf(a.x);
    r.y = __builtin_amdgcn_rcpf(a.y);
    return r;
}

// Packed-f32 LSTM update on a pair of units. Gates pre-scaled by log2e
// (g-gate by 2*log2e).
__device__ __forceinline__ f2v lstm_pair(f2v aI, f2v aF, f2v aG, f2v aO, f2v& cst) {
    const f2v one = {1.f, 1.f};
    f2v ei = nexp2c(aI);
    f2v ef = nexp2c(aF);
    f2v eg = nexp2c(aG);
    f2v eo = nexp2c(aO);
    f2v p   = (one + ei) * (one + eg);
    f2v num = cst * p + (one - eg) * (one + ef);
    f2v den = (one + ef) * p;
    f2v c2  = num * rcp2(den);
    cst = c2;
    f2v t2 = c2 * (f2v){2.f * L2E, 2.f * L2E};
    f2v e2 = nexp2c(t2);
    return (one - e2) * rcp2((one + eo) * (one + e2));
}

// pin 12 weight fragments (encoder)
#define PINW(W)                                                               \
    asm volatile("" : "+v"(W[0][0]), "+v"(W[0][1]), "+v"(W[0][2]),            \
                      "+v"(W[1][0]), "+v"(W[1][1]), "+v"(W[1][2]));           \
    asm volatile("" : "+v"(W[2][0]), "+v"(W[2][1]), "+v"(W[2][2]),            \
                      "+v"(W[3][0]), "+v"(W[3][1]), "+v"(W[3][2]));

// pin 24 weight fragments (decoder)
#define PINW24(W)                                                             \
    asm volatile("" : "+v"(W[0][0]), "+v"(W[0][1]), "+v"(W[0][2]),            \
                      "+v"(W[1][0]), "+v"(W[1][1]), "+v"(W[1][2]));           \
    asm volatile("" : "+v"(W[2][0]), "+v"(W[2][1]), "+v"(W[2][2]),            \
                      "+v"(W[3][0]), "+v"(W[3][1]), "+v"(W[3][2]));           \
    asm volatile("" : "+v"(W[4][0]), "+v"(W[4][1]), "+v"(W[4][2]),            \
                      "+v"(W[5][0]), "+v"(W[5][1]), "+v"(W[5][2]));           \
    asm volatile("" : "+v"(W[6][0]), "+v"(W[6][1]), "+v"(W[6][2]),            \
                      "+v"(W[7][0]), "+v"(W[7][1]), "+v"(W[7][2]));

// ---------------------------------------------------------------------------
// Prep: weights -> fragment-ordered RNE bf16, pre-scaled by log2e
// (g-gate rows by 2*log2e). [grp][cell(4)][nt(8)][ki(3)][lane(64)][j(8)]
//   gate = nt*16 + (lane&15); k = ki*32 + (lane>>4)*8 + j
// ---------------------------------------------------------------------------
__global__ void prep_kernel(const float* __restrict__ eWih, const float* __restrict__ eWhh,
                            const float* __restrict__ dWih, const float* __restrict__ dWhh,
                            unsigned short* __restrict__ ws)
{
    int fid = blockIdx.x * 256 + threadIdx.x;
    if (fid >= 12288) return;
    int lane = fid & 63;
    int ki   = (fid >> 6) % 3;
    int nt   = (fid / 192) & 7;
    int cell = (fid / 1536) & 3;
    int grp  = fid / 6144;
    const float* Wih = grp ? dWih : eWih;
    const float* Whh = grp ? dWhh : eWhh;
    int gate = nt * 16 + (lane & 15);
    float scale = ((gate >> 5) == 2) ? 2.f * L2E : L2E;
    int k0 = ki * 32 + (lane >> 4) * 8;
    size_t base = (size_t)grp * 98304 + (size_t)cell * 12288 + nt * 1536 + ki * 512 + lane * 8;
#pragma unroll
    for (int j = 0; j < 8; ++j) {
        int k = k0 + j;
        float v = (k < 64) ? Wih[(size_t)cell * 8192 + gate * 64 + k]
                           : Whh[(size_t)cell * 4096 + gate * 32 + (k - 64)];
        ws[base + j] = rne_bf16(v * scale);
    }
}

// ---------------------------------------------------------------------------
// Encoder layer (verbatim R12, best-measured): block = 256 thr (4 waves =
// dir x q-half), 16 rows, grid 512. x-part MFMAs of t+1 hoisted pre-barrier.
// ---------------------------------------------------------------------------
template<int IS_L0>
__global__ __launch_bounds__(256, 2)
void enc_kernel(const float* __restrict__ X, const unsigned short* __restrict__ Xh,
                const float* __restrict__ h0, const float* __restrict__ c0,
                const unsigned short* __restrict__ Whi, const float* __restrict__ bias,
                int layer, unsigned short* __restrict__ outh, float* __restrict__ z)
{
    __shared__ __align__(16) unsigned short Hsh[2][2][16][40];   // [dir][parity][row][unit]
    const int tid = threadIdx.x, w = tid >> 6, lane = tid & 63;
    const int d = w >> 1, q = w & 1;
    const int a = lane & 15, kb = lane >> 4;
    const int u = q * 16 + a;
    const int row0 = blockIdx.x * 16;
    const int ci = 2 * layer + d;

    bf8v WH[4][3];   // 12 frags = 48 VGPR, pinned
#pragma unroll
    for (int g = 0; g < 4; ++g)
#pragma unroll
        for (int ki = 0; ki < 3; ++ki)
            WH[g][ki] = *(const bf8v*)(Whi + (size_t)ci * 12288 + (2 * g + q) * 1536
                                       + ki * 512 + lane * 8);
    float bj[4];
#pragma unroll
    for (int g = 0; g < 4; ++g)
        bj[g] = bias[ci * 128 + g * 32 + u] * ((g == 2) ? 2.f * L2E : L2E);
    float cst[4], hfin[4];
#pragma unroll
    for (int j = 0; j < 4; ++j)
        cst[j] = c0[((size_t)ci * Bn + row0 + 4 * kb + j) * Hn + u];

    {   // h0 -> parity 1
        int dd = tid >> 7, rr = (tid >> 3) & 15, u4 = (tid & 7) * 4;
        const float* src = h0 + ((size_t)(2 * layer + dd) * Bn + row0 + rr) * Hn + u4;
#pragma unroll
        for (int e = 0; e < 4; ++e)
            Hsh[dd][1][rr][u4 + e] = rne_bf16(src[e]);
    }
    __syncthreads();

    const int grow = row0 + a;
    float4 p0, p1, p2, p3; bf8v ph0, ph1;
    f4v acc[4];
    {   // t = 0: load x, build acc = bias + x-part; prefetch t = 1
        int tt = d ? (Tn - 1) : 0;
        bf8v xf0, xf1;
        if (IS_L0) {
            const float* sp = X + ((size_t)grow * Tn + tt) * Fn;
            xf0 = rne8(*(const float4*)(sp + kb * 8), *(const float4*)(sp + kb * 8 + 4));
            xf1 = rne8(*(const float4*)(sp + 32 + kb * 8), *(const float4*)(sp + 32 + kb * 8 + 4));
        } else {
            size_t so = ((size_t)tt * Bn + grow) * Fn + kb * 8;
            xf0 = *(const bf8v*)(Xh + so);
            xf1 = *(const bf8v*)(Xh + so + 32);
        }
#pragma unroll
        for (int g = 0; g < 4; ++g) {
            acc[g] = (f4v){bj[g], bj[g], bj[g], bj[g]};
            acc[g] = mfma_bf16(xf0, WH[g][0], acc[g]);
            acc[g] = mfma_bf16(xf1, WH[g][1], acc[g]);
        }
        int tt1 = d ? (Tn - 2) : 1;
        if (IS_L0) {
            const float* sp = X + ((size_t)grow * Tn + tt1) * Fn;
            p0 = *(const float4*)(sp + kb * 8);      p1 = *(const float4*)(sp + kb * 8 + 4);
            p2 = *(const float4*)(sp + 32 + kb * 8); p3 = *(const float4*)(sp + 32 + kb * 8 + 4);
        } else {
            size_t so = ((size_t)tt1 * Bn + grow) * Fn + kb * 8;
            ph0 = *(const bf8v*)(Xh + so);
            ph1 = *(const bf8v*)(Xh + so + 32);
        }
    }

    for (int t = 0; t < Tn; ++t) {
        PINW(WH);
        bf8v hh = *(const bf8v*)&Hsh[d][(t & 1) ^ 1][a][kb * 8];
#pragma unroll
        for (int g = 0; g < 4; ++g) acc[g] = mfma_bf16(hh, WH[g][2], acc[g]);
        int tp = d ? (Tn - 1 - t) : t;
#pragma unroll
        for (int jp = 0; jp < 2; ++jp) {
            f2v aI = {acc[0][2 * jp], acc[0][2 * jp + 1]};
            f2v aF = {acc[1][2 * jp], acc[1][2 * jp + 1]};
            f2v aG = {acc[2][2 * jp], acc[2][2 * jp + 1]};
            f2v aO = {acc[3][2 * jp], acc[3][2 * jp + 1]};
            f2v cc = {cst[2 * jp], cst[2 * jp + 1]};
            f2v hv = lstm_pair(aI, aF, aG, aO, cc);
            cst[2 * jp] = cc.x;  cst[2 * jp + 1] = cc.y;
            hfin[2 * jp] = hv.x; hfin[2 * jp + 1] = hv.y;
            unsigned short hp0 = rne_bf16(hv.x), hp1 = rne_bf16(hv.y);
            Hsh[d][t & 1][4 * kb + 2 * jp][u]     = hp0;
            Hsh[d][t & 1][4 * kb + 2 * jp + 1][u] = hp1;
            if (IS_L0) {
                outh[((size_t)tp * Bn + row0 + 4 * kb + 2 * jp) * Fn + d * 32 + u]     = hp0;
                outh[((size_t)tp * Bn + row0 + 4 * kb + 2 * jp + 1) * Fn + d * 32 + u] = hp1;
            }
        }
        {   // pre-barrier: x-part of t+1 + prefetch t+2
            bf8v xf0, xf1;
            if (IS_L0) { xf0 = rne8(p0, p1); xf1 = rne8(p2, p3); }
            else       { xf0 = ph0; xf1 = ph1; }
#pragma unroll
            for (int g = 0; g < 4; ++g) {
                f4v t0 = (f4v){bj[g], bj[g], bj[g], bj[g]};
                t0 = mfma_bf16(xf0, WH[g][0], t0);
                acc[g] = mfma_bf16(xf1, WH[g][1], t0);
            }
            int ts = (t + 2 < Tn) ? t + 2 : Tn - 1;
            int tt = d ? (Tn - 1 - ts) : ts;
            if (IS_L0) {
                const float* sp = X + ((size_t)grow * Tn + tt) * Fn;
                p0 = *(const float4*)(sp + kb * 8);      p1 = *(const float4*)(sp + kb * 8 + 4);
                p2 = *(const float4*)(sp + 32 + kb * 8); p3 = *(const float4*)(sp + 32 + kb * 8 + 4);
            } else {
                size_t so = ((size_t)tt * Bn + grow) * Fn + kb * 8;
                ph0 = *(const bf8v*)(Xh + so);
                ph1 = *(const bf8v*)(Xh + so + 32);
            }
        }
        lds_barrier_pinned();
    }
#pragma unroll
    for (int j = 0; j < 4; ++j) {
        size_t zr = (size_t)(row0 + 4 * kb + j) * 256;
        z[zr + ci * 32 + u]       = hfin[j];
        z[zr + 128 + ci * 32 + u] = cst[j];
    }
}

// ---------------------------------------------------------------------------
// Decoder v2: block = 256 thr (4 waves: phase P x cell-half cl), 16 rows,
// grid 512 -> TWO independent barrier domains per CU (the encoder's winning
// property). Wave owns ALL 8 gate-tiles of its cell (96 weight VGPR, pinned).
// Schedule/step: even slot = A finish L0(t) || B hpart; barrier;
//                odd slot  = B finish L1(t) || A hpart(t+1); barrier.
// hpart reads are wave-private h -> no extra sync. 2 barriers/step.
// ---------------------------------------------------------------------------
__global__ __launch_bounds__(256, 2)
void dec_kernel(const unsigned short* __restrict__ Whi, const float* __restrict__ bias,
                const float* __restrict__ z, float* __restrict__ xhat)
{
    __shared__ __align__(16) unsigned short Ysh[2][16][72];     // [par][row][feat]
    __shared__ __align__(16) unsigned short Msh[16][72];        // [row][feat]
    __shared__ __align__(16) unsigned short Hsh[4][2][16][40];  // [cell][par][row][unit]

    const int tid = threadIdx.x, w = tid >> 6, lane = tid & 63;
    const int P = w >> 1, cl = w & 1;
    const int cell = P * 2 + cl;
    const int a = lane & 15, kb = lane >> 4;
    const int row0 = blockIdx.x * 16;

    bf8v WH[8][3];   // 24 frags = 96 VGPR, pinned
#pragma unroll
    for (int nt = 0; nt < 8; ++nt)
#pragma unroll
        for (int ki = 0; ki < 3; ++ki)
            WH[nt][ki] = *(const bf8v*)(Whi + (size_t)cell * 12288 + nt * 1536
                                        + ki * 512 + lane * 8);
    f4v bC[4][2];    // bias splats, MFMA C-operand
#pragma unroll
    for (int g = 0; g < 4; ++g)
#pragma unroll
        for (int s = 0; s < 2; ++s) {
            float bv = bias[cell * 128 + g * 32 + s * 16 + a] * ((g == 2) ? 2.f * L2E : L2E);
            bC[g][s] = (f4v){bv, bv, bv, bv};
        }

    float cst[2][4];   // [unit-half s][j]
#pragma unroll
    for (int s = 0; s < 2; ++s)
#pragma unroll
        for (int j = 0; j < 4; ++j)
            cst[s][j] = z[(size_t)(row0 + 4 * kb + j) * 256 + 128 + cell * 32 + s * 16 + a];

    {   // h-init -> parity 1: 4 cells x 16 rows x 32 units / 256 thr = 8 each
        int ct = tid >> 6, rr = (tid >> 2) & 15, u8 = (tid & 3) * 8;
        const float* src = z + (size_t)(row0 + rr) * 256 + ct * 32 + u8;
#pragma unroll
        for (int e = 0; e < 8; ++e)
            Hsh[ct][1][rr][u8 + e] = rne_bf16(src[e]);
    }
    __syncthreads();

    f4v accp[4][2];
    // h-part precompute (wave-private h); bias enters as C-operand.
    auto hpart = [&](int rpar) {
        bf8v hh = *(const bf8v*)&Hsh[cell][rpar][a][kb * 8];
        __builtin_amdgcn_s_setprio(1);
#pragma unroll
        for (int g = 0; g < 4; ++g)
#pragma unroll
            for (int s = 0; s < 2; ++s)
                accp[g][s] = mfma_bf16(hh, WH[2 * g + s][2], bC[g][s]);
        __builtin_amdgcn_s_setprio(0);
    };
    // post-barrier finish: V-read -> 16 MFMA -> lstm x8 -> writes. par == t&1.
    auto finish = [&](int t, int par, bool isA, bool hasV) {
        if (hasV) {
            const unsigned short (*Vh)[72] = isA ? Ysh[par ^ 1] : Msh;
            bf8v vh0 = *(const bf8v*)&Vh[a][kb * 8];
            bf8v vh1 = *(const bf8v*)&Vh[a][32 + kb * 8];
            __builtin_amdgcn_s_setprio(1);
#pragma unroll
            for (int g = 0; g < 4; ++g)
#pragma unroll
                for (int s = 0; s < 2; ++s) {
                    accp[g][s] = mfma_bf16(vh0, WH[2 * g + s][0], accp[g][s]);
                    accp[g][s] = mfma_bf16(vh1, WH[2 * g + s][1], accp[g][s]);
                }
            __builtin_amdgcn_s_setprio(0);
        }
#pragma unroll
        for (int s = 0; s < 2; ++s) {
            const int u = s * 16 + a;
#pragma unroll
            for (int jp = 0; jp < 2; ++jp) {
                f2v aI = {accp[0][s][2 * jp], accp[0][s][2 * jp + 1]};
                f2v aF = {accp[1][s][2 * jp], accp[1][s][2 * jp + 1]};
                f2v aG = {accp[2][s][2 * jp], accp[2][s][2 * jp + 1]};
                f2v aO = {accp[3][s][2 * jp], accp[3][s][2 * jp + 1]};
                f2v cc = {cst[s][2 * jp], cst[s][2 * jp + 1]};
                f2v hv = lstm_pair(aI, aF, aG, aO, cc);
                cst[s][2 * jp] = cc.x;  cst[s][2 * jp + 1] = cc.y;
                unsigned short hp0 = rne_bf16(hv.x), hp1 = rne_bf16(hv.y);
                int r0 = 4 * kb + 2 * jp, r1 = r0 + 1;
                Hsh[cell][par][r0][u] = hp0;
                Hsh[cell][par][r1][u] = hp1;
                if (isA) {
                    Msh[r0][cl * 32 + u] = hp0;
                    Msh[r1][cl * 32 + u] = hp1;
                } else {
                    Ysh[par][r0][cl * 32 + u] = hp0;
                    Ysh[par][r1][cl * 32 + u] = hp1;
                    xhat[((size_t)(row0 + r0) * Tn + t) * Fn + cl * 32 + u] = hv.x;
                    xhat[((size_t)(row0 + r1) * Tn + t) * Fn + cl * 32 + u] = hv.y;
                }
            }
        }
    };

    hpart(1);   // prologue: both phases' first work item uses h(init) at par 1
    for (int it = 0; it < Tn / 2; ++it) {
        const int t0 = 2 * it, t1 = t0 + 1;
        const bool nz = (it > 0);
        PINW24(WH);
        // ---- t0 (par 0) ---- even: A finish L0(t0) [V=y@par1] | B hpart L1(t0)
        if (P == 0) finish(t0, 0, true, nz);
        else        hpart(1);
        lds_barrier_relaxed();
        //                      odd:  B finish L1(t0) [V=m]      | A hpart L0(t1)
        if (P == 1) finish(t0, 0, false, true);
        else        hpart(0);
        lds_barrier_relaxed();
        PINW24(WH);
        // ---- t1 (par 1) ---- even: A finish L0(t1) [V=y@par0] | B hpart L1(t1)
        if (P == 0) finish(t1, 1, true, true);
        else        hpart(0);
        lds_barrier_relaxed();
        //                      odd:  B finish L1(t1) [V=m]      | A hpart L0(t0+2)
        if (P == 1) finish(t1, 1, false, true);
        else        hpart(1);
        lds_barrier_relaxed();
    }
}

extern "C" void kernel_launch(void* const* d_in, const int* in_sizes, int n_in,
                              void* d_out, int out_size, void* d_ws, size_t ws_size,
                              hipStream_t stream) {
    const float* x    = (const float*)d_in[0];
    const float* h0   = (const float*)d_in[1];
    const float* c0   = (const float*)d_in[2];
    const float* eWih = (const float*)d_in[3];
    const float* eWhh = (const float*)d_in[4];
    const float* eb   = (const float*)d_in[5];
    const float* dWih = (const float*)d_in[6];
    const float* dWhh = (const float*)d_in[7];
    const float* db   = (const float*)d_in[8];

    float* out = (float*)d_out;
    unsigned short* xs1h = (unsigned short*)d_out;          // [T,B,64] bf16 plane
    float* zb = out + (size_t)XHAT_ELEMS;                   // [B,256] latent
    unsigned short* wsb = (unsigned short*)d_ws;            // weight fragments

    hipLaunchKernelGGL(prep_kernel, dim3(48), dim3(256), 0, stream,
                       eWih, eWhh, dWih, dWhh, wsb);
    // encoder layer 0: x -> xs1 plane + z slots 0,1
    hipLaunchKernelGGL((enc_kernel<1>), dim3(Bn / 16), dim3(256), 0, stream,
                       x, (const unsigned short*)nullptr,
                       h0, c0, wsb, eb, 0, xs1h, zb);
    // encoder layer 1: xs1 plane -> z slots 2,3
    hipLaunchKernelGGL((enc_kernel<0>), dim3(Bn / 16), dim3(256), 0, stream,
                       (const float*)nullptr, xs1h,
                       h0, c0, wsb, eb, 1, (unsigned short*)nullptr, zb);
    // decoder: z -> x_hat (overwrites xs1 region)
    hipLaunchKernelGGL(dec_kernel, dim3(Bn / 16), dim3(256), 0, stream,
                       wsb + 98304, db, zb, out);
}